// Round 5
// baseline (93.251 us; speedup 1.0000x reference)
//
#include <hip/hip_runtime.h>

typedef float f4 __attribute__((ext_vector_type(4)));
typedef float f4u __attribute__((ext_vector_type(4), aligned(4)));

struct M3 { float m[3][3]; };

#define ELEM(q, n) ((q)[(n) >> 2][(n) & 3])

__device__ __forceinline__ M3 matmul(const M3& A, const M3& B) {  // A @ B
  M3 C;
#pragma unroll
  for (int i = 0; i < 3; ++i)
#pragma unroll
    for (int j = 0; j < 3; ++j)
      C.m[i][j] = A.m[i][0]*B.m[0][j] + A.m[i][1]*B.m[1][j] + A.m[i][2]*B.m[2][j];
  return C;
}

__device__ __forceinline__ M3 shfl_mat(const M3& A, int srcLane) {
  M3 C;
#pragma unroll
  for (int i = 0; i < 3; ++i)
#pragma unroll
    for (int j = 0; j < 3; ++j)
      C.m[i][j] = __shfl(A.m[i][j], srcLane, 64);
  return C;
}

// fwd lane: matrix kf of the group, as-is. back lane: matrix kb of the group, transposed.
__device__ __forceinline__ M3 build_D(const f4 (&q)[9], int kf, int kb, bool tb) {
  M3 D;
#pragma unroll
  for (int i = 0; i < 3; ++i)
#pragma unroll
    for (int j = 0; j < 3; ++j) {
      float a = ELEM(q, 9*kf + 3*i + j);
      float c = ELEM(q, 9*kb + 3*j + i);
      D.m[i][j] = tb ? c : a;
    }
  return D;
}

__device__ __forceinline__ float sigm(float z) {
  return __builtin_amdgcn_rcpf(1.0f + __expf(-z));
}
__device__ __forceinline__ float tanh_(float z) {
  float e = __expf(2.0f * z);
  return 1.0f - 2.0f * __builtin_amdgcn_rcpf(e + 1.0f);
}

__device__ __forceinline__ void lstm_step(
    float x0, float x1, float x2,
    float& h0, float& h1, float& h2,
    float& c0, float& c1, float& c2,
    const float (&wi)[12][3], const float (&wh)[12][3], const float (&bs)[12]) {
  float g[12];
#pragma unroll
  for (int k = 0; k < 12; ++k) {
    g[k] = bs[k] + wi[k][0]*x0 + wi[k][1]*x1 + wi[k][2]*x2
                 + wh[k][0]*h0 + wh[k][1]*h1 + wh[k][2]*h2;
  }
  float i0 = sigm(g[0]),  i1 = sigm(g[1]),  i2 = sigm(g[2]);
  float f0 = sigm(g[3]),  f1 = sigm(g[4]),  f2 = sigm(g[5]);
  float t0 = tanh_(g[6]), t1 = tanh_(g[7]), t2 = tanh_(g[8]);
  float o0 = sigm(g[9]),  o1 = sigm(g[10]), o2 = sigm(g[11]);
  c0 = f0*c0 + i0*t0; c1 = f1*c1 + i1*t1; c2 = f2*c2 + i2*t2;
  h0 = o0*tanh_(c0); h1 = o1*tanh_(c1); h2 = o2*tanh_(c2);
}

#define EPB 16  // elements per block (block = 256 threads, 16 lanes/element)

// Phase 1: segmented matrix-prefix scan produces all dirs rows (as round 4).
// Back lanes also deposit their 8 rows into LDS [t][e].
// Phase 2 (after barrier): lanes 0..15 each run one element's 65-step LSTM
// entirely in-lane (no shuffles), x streamed from LDS.
__global__ __launch_bounds__(256) void fused_kernel(
    const float* __restrict__ dir, const float* __restrict__ R,
    const float* __restrict__ Wih, const float* __restrict__ Whh,
    const float* __restrict__ bih, const float* __restrict__ bhh,
    float* __restrict__ out, int B) {
  __shared__ f4 xrows[64 * EPB];  // 16 KB: back rows, [t][e] layout

  const int tid = threadIdx.x;
  const int lane = tid & 63;            // lane within wave (for shuffles)
  const int l = tid & 15;
  const int s = l & 7;
  const bool tb = (l < 8);              // back-chain lane
  const bool skip = (!tb) && (s == 7);  // fwd segment 7 has only 7 frames
  const int eloc = tid >> 4;            // block-local element 0..15
  const int b = blockIdx.x * EPB + eloc;
  const bool valid = (b < B);

  f4 qa[9], qb[9];
  float d0 = 0.f, d1 = 0.f, d2 = 0.f;
  if (valid) {
    const float* Rb = R + (size_t)b * 1152;
    const int lo = tb ? (56 - 8*s) : (64 + 8*s);
    const int gA = tb ? lo + 4 : lo;   // group supplying D0..D3
    const int gB = tb ? lo : lo + 4;   // group supplying D4..D7
    const f4* pA = (const f4*)(Rb + gA * 9);
    const f4* pB = (const f4*)(Rb + gB * 9);
#pragma unroll
    for (int i = 0; i < 9; ++i) { qa[i] = pA[i]; qb[i] = pB[i]; }
    d0 = dir[3*b+0]; d1 = dir[3*b+1]; d2 = dir[3*b+2];
  } else {
#pragma unroll
    for (int i = 0; i < 9; ++i) { qa[i] = (f4){0,0,0,0}; qb[i] = (f4){0,0,0,0}; }
  }

  // ---- segment product S = D7 @ ... @ D0 ----
  M3 S = build_D(qa, 0, 3, tb);
#pragma unroll
  for (int j = 1; j < 4; ++j) S = matmul(build_D(qa, j, 3 - j, tb), S);
#pragma unroll
  for (int j = 0; j < 4; ++j) S = matmul(build_D(qb, j, 3 - j, tb), S);
  // (skip lane includes frame 127 in S; its scan result is never consumed)

  // ---- Hillis-Steele inclusive scan over the 8-lane subgroup ----
  M3 I = S;
#pragma unroll
  for (int d = 1; d < 8; d <<= 1) {
    M3 Sh = shfl_mat(I, lane - d);
    M3 T = matmul(I, Sh);
#pragma unroll
    for (int i = 0; i < 3; ++i)
#pragma unroll
      for (int j = 0; j < 3; ++j)
        I.m[i][j] = (s >= d) ? T.m[i][j] : I.m[i][j];
  }

  float w0 = I.m[0][0]*d0 + I.m[0][1]*d1 + I.m[0][2]*d2;
  float w1 = I.m[1][0]*d0 + I.m[1][1]*d1 + I.m[1][2]*d2;
  float w2 = I.m[2][0]*d0 + I.m[2][1]*d1 + I.m[2][2]*d2;
  float p0 = __shfl(w0, lane - 1, 64);
  float p1 = __shfl(w1, lane - 1, 64);
  float p2 = __shfl(w2, lane - 1, 64);
  float v0 = (s == 0) ? d0 : p0;
  float v1 = (s == 0) ? d1 : p1;
  float v2 = (s == 0) ? d2 : p2;

  // ---- rows by chaining v <- D_j @ v ----
  float row[24];
#pragma unroll
  for (int j = 0; j < 8; ++j) {
    M3 D = (j < 4) ? build_D(qa, j, 3 - j, tb) : build_D(qb, j - 4, 7 - j, tb);
    float n0 = D.m[0][0]*v0 + D.m[0][1]*v1 + D.m[0][2]*v2;
    float n1 = D.m[1][0]*v0 + D.m[1][1]*v1 + D.m[1][2]*v2;
    float n2 = D.m[2][0]*v0 + D.m[2][1]*v1 + D.m[2][2]*v2;
    v0 = n0; v1 = n1; v2 = n2;
    row[3*j+0] = n0; row[3*j+1] = n1; row[3*j+2] = n2;
  }

  if (valid) {
    float* obE = out + (size_t)b * 384;
    const int rowBase = tb ? 8*s : 65 + 8*s;
    float* ob = obE + (size_t)rowBase * 3;
#pragma unroll
    for (int kk = 0; kk < 5; ++kk) {
      f4u vv = { row[4*kk+0], row[4*kk+1], row[4*kk+2], row[4*kk+3] };
      *(f4u*)(ob + 4*kk) = vv;
    }
    ob[20] = row[20];
    if (!skip) { ob[21] = row[21]; ob[22] = row[22]; ob[23] = row[23]; }
  }

  // back lanes deposit rows into LDS for the LSTM phase
  if (tb) {
#pragma unroll
    for (int j = 0; j < 8; ++j) {
      f4 vv = { row[3*j+0], row[3*j+1], row[3*j+2], 0.f };
      xrows[(8*s + j) * EPB + eloc] = vv;
    }
  }

  __syncthreads();

  // ---- Phase 2: per-lane LSTM, lanes 0..15 of wave 0 ----
  if (tid < EPB) {
    const int b2 = blockIdx.x * EPB + tid;
    if (b2 < B) {
      float wi[12][3], wh[12][3], bs[12];
#pragma unroll
      for (int k = 0; k < 12; ++k) {
#pragma unroll
        for (int j = 0; j < 3; ++j) { wi[k][j] = Wih[k*3+j]; wh[k][j] = Whh[k*3+j]; }
        bs[k] = bih[k] + bhh[k];
      }
      const float dd0 = dir[3*b2+0], dd1 = dir[3*b2+1], dd2 = dir[3*b2+2];
      float h0 = 0.f, h1 = 0.f, h2 = 0.f, c0 = 0.f, c1 = 0.f, c2 = 0.f;
#pragma unroll 4
      for (int t = 0; t < 64; ++t) {
        f4 x = xrows[t * EPB + tid];
        lstm_step(x[0], x[1], x[2], h0, h1, h2, c0, c1, c2, wi, wh, bs);
      }
      lstm_step(dd0, dd1, dd2, h0, h1, h2, c0, c1, c2, wi, wh, bs);
      float* obE = out + (size_t)b2 * 384;
      obE[192] = h0; obE[193] = h1; obE[194] = h2;
    }
  }
}

extern "C" void kernel_launch(void* const* d_in, const int* in_sizes, int n_in,
                              void* d_out, int out_size, void* d_ws, size_t ws_size,
                              hipStream_t stream) {
  const float* dir = (const float*)d_in[0];
  const float* R   = (const float*)d_in[1];
  const float* Wih = (const float*)d_in[2];
  const float* Whh = (const float*)d_in[3];
  const float* bih = (const float*)d_in[4];
  const float* bhh = (const float*)d_in[5];
  float* out = (float*)d_out;

  const int B = in_sizes[0] / 3;  // 16384
  const int grid = (B + EPB - 1) / EPB;  // 1024 blocks of 256 threads
  hipLaunchKernelGGL(fused_kernel, dim3(grid), dim3(256), 0, stream,
                     dir, R, Wih, Whh, bih, bhh, out, B);
}

// Round 6
// 36.706 us; speedup vs baseline: 2.5405x; 2.5405x over previous
//
#include <hip/hip_runtime.h>

typedef float f4 __attribute__((ext_vector_type(4)));
typedef float f4u __attribute__((ext_vector_type(4), aligned(4)));

struct M3 { float m[3][3]; };

#define ELEM(q, n) ((q)[(n) >> 2][(n) & 3])

__device__ __forceinline__ M3 matmul(const M3& A, const M3& B) {  // A @ B
  M3 C;
#pragma unroll
  for (int i = 0; i < 3; ++i)
#pragma unroll
    for (int j = 0; j < 3; ++j)
      C.m[i][j] = A.m[i][0]*B.m[0][j] + A.m[i][1]*B.m[1][j] + A.m[i][2]*B.m[2][j];
  return C;
}

__device__ __forceinline__ M3 shfl_mat(const M3& A, int srcLane) {
  M3 C;
#pragma unroll
  for (int i = 0; i < 3; ++i)
#pragma unroll
    for (int j = 0; j < 3; ++j)
      C.m[i][j] = __shfl(A.m[i][j], srcLane, 64);
  return C;
}

// fwd lane: matrix kf of the group, as-is. back lane: matrix kb of the group, transposed.
__device__ __forceinline__ M3 build_D(const f4 (&q)[9], int kf, int kb, bool tb) {
  M3 D;
#pragma unroll
  for (int i = 0; i < 3; ++i)
#pragma unroll
    for (int j = 0; j < 3; ++j) {
      float a = ELEM(q, 9*kf + 3*i + j);
      float c = ELEM(q, 9*kb + 3*j + i);
      D.m[i][j] = tb ? c : a;
    }
  return D;
}

__device__ __forceinline__ float sigm(float z) {
  return __builtin_amdgcn_rcpf(1.0f + __expf(-z));
}
__device__ __forceinline__ float tanh_(float z) {
  float e = __expf(2.0f * z);
  return 1.0f - 2.0f * __builtin_amdgcn_rcpf(e + 1.0f);
}

// quad_perm broadcast: CTRL 0x00 -> lane0 of quad, 0x55 -> lane1, 0xAA -> lane2
template <int CTRL>
__device__ __forceinline__ float quad_bcast(float v) {
  return __int_as_float(
      __builtin_amdgcn_mov_dpp(__float_as_int(v), CTRL, 0xf, 0xf, true));
}

#define EPB 16  // elements per block (block = 256 threads, 16 scan-lanes/element)
// LDS x-row layout: swizzled so writes are 4-way, reads 2-way(free)
#define XIDX(t, e) ((t)*17 + 2*((t) >> 3) + (e))

__global__ __launch_bounds__(256) void fused_kernel(
    const float* __restrict__ dir, const float* __restrict__ R,
    const float* __restrict__ Wih, const float* __restrict__ Whh,
    const float* __restrict__ bih, const float* __restrict__ bhh,
    float* __restrict__ out, int B) {
  __shared__ f4 xrows[64 * 17 + 2 * 7 + 16];  // ~17.4 KB

  const int tid = threadIdx.x;
  const int lane = tid & 63;
  const int l = tid & 15;
  const int s = l & 7;
  const bool tb = (l < 8);              // back-chain lane
  const bool skip = (!tb) && (s == 7);  // fwd segment 7 has only 7 frames
  const int eloc = tid >> 4;            // block-local element 0..15
  const int b = blockIdx.x * EPB + eloc;
  const bool valid = (b < B);

  // ================= Phase 1: segmented matrix-prefix scan =================
  f4 qa[9], qb[9];
  float d0 = 0.f, d1 = 0.f, d2 = 0.f;
  if (valid) {
    const float* Rb = R + (size_t)b * 1152;
    const int lo = tb ? (56 - 8*s) : (64 + 8*s);
    const int gA = tb ? lo + 4 : lo;   // group supplying D0..D3
    const int gB = tb ? lo : lo + 4;   // group supplying D4..D7
    const f4* pA = (const f4*)(Rb + gA * 9);
    const f4* pB = (const f4*)(Rb + gB * 9);
#pragma unroll
    for (int i = 0; i < 9; ++i) { qa[i] = pA[i]; qb[i] = pB[i]; }
    d0 = dir[3*b+0]; d1 = dir[3*b+1]; d2 = dir[3*b+2];
  } else {
#pragma unroll
    for (int i = 0; i < 9; ++i) { qa[i] = (f4){0,0,0,0}; qb[i] = (f4){0,0,0,0}; }
  }

  // segment product S = D7 @ ... @ D0
  M3 S = build_D(qa, 0, 3, tb);
#pragma unroll
  for (int j = 1; j < 4; ++j) S = matmul(build_D(qa, j, 3 - j, tb), S);
#pragma unroll
  for (int j = 0; j < 4; ++j) S = matmul(build_D(qb, j, 3 - j, tb), S);

  // Hillis-Steele inclusive scan over the 8-lane subgroup
  M3 I = S;
#pragma unroll
  for (int d = 1; d < 8; d <<= 1) {
    M3 Sh = shfl_mat(I, lane - d);
    M3 T = matmul(I, Sh);
#pragma unroll
    for (int i = 0; i < 3; ++i)
#pragma unroll
      for (int j = 0; j < 3; ++j)
        I.m[i][j] = (s >= d) ? T.m[i][j] : I.m[i][j];
  }

  float w0 = I.m[0][0]*d0 + I.m[0][1]*d1 + I.m[0][2]*d2;
  float w1 = I.m[1][0]*d0 + I.m[1][1]*d1 + I.m[1][2]*d2;
  float w2 = I.m[2][0]*d0 + I.m[2][1]*d1 + I.m[2][2]*d2;
  float p0 = __shfl(w0, lane - 1, 64);
  float p1 = __shfl(w1, lane - 1, 64);
  float p2 = __shfl(w2, lane - 1, 64);
  float v0 = (s == 0) ? d0 : p0;
  float v1 = (s == 0) ? d1 : p1;
  float v2 = (s == 0) ? d2 : p2;

  // rows by chaining v <- D_j @ v
  float row[24];
#pragma unroll
  for (int j = 0; j < 8; ++j) {
    M3 D = (j < 4) ? build_D(qa, j, 3 - j, tb) : build_D(qb, j - 4, 7 - j, tb);
    float n0 = D.m[0][0]*v0 + D.m[0][1]*v1 + D.m[0][2]*v2;
    float n1 = D.m[1][0]*v0 + D.m[1][1]*v1 + D.m[1][2]*v2;
    float n2 = D.m[2][0]*v0 + D.m[2][1]*v1 + D.m[2][2]*v2;
    v0 = n0; v1 = n1; v2 = n2;
    row[3*j+0] = n0; row[3*j+1] = n1; row[3*j+2] = n2;
  }

  if (valid) {
    float* obE = out + (size_t)b * 384;
    const int rowBase = tb ? 8*s : 65 + 8*s;
    float* ob = obE + (size_t)rowBase * 3;
#pragma unroll
    for (int kk = 0; kk < 5; ++kk) {
      f4u vv = { row[4*kk+0], row[4*kk+1], row[4*kk+2], row[4*kk+3] };
      *(f4u*)(ob + 4*kk) = vv;
    }
    ob[20] = row[20];
    if (!skip) { ob[21] = row[21]; ob[22] = row[22]; ob[23] = row[23]; }
  }

  // back lanes deposit rows into LDS (x_t for the LSTM), swizzled layout
  if (tb) {
#pragma unroll
    for (int n = 0; n < 8; ++n) {
      f4 vv = { row[3*n+0], row[3*n+1], row[3*n+2], 0.f };
      xrows[XIDX(8*s + n, eloc)] = vv;
    }
  }

  __syncthreads();

  // ================= Phase 2: quad-lane LSTM (one wave per block) ==========
  const int lstm_wave = blockIdx.x & 3;  // decorrelate SIMD placement
  if ((tid >> 6) != lstm_wave) return;

  const int e2 = lane >> 2;            // element 0..15
  const int u = lane & 3;              // hidden unit (lane 3 duplicates unit 0)
  const int uu = (u == 3) ? 0 : u;
  const int b2 = blockIdx.x * EPB + e2;
  const bool valid2 = (b2 < B);
  const int b2c = valid2 ? b2 : 0;

  // this lane's 4 gate rows: i=uu, f=3+uu, g=6+uu, o=9+uu
  const float wii0 = Wih[uu*3+0],     wii1 = Wih[uu*3+1],     wii2 = Wih[uu*3+2];
  const float wif0 = Wih[(3+uu)*3+0], wif1 = Wih[(3+uu)*3+1], wif2 = Wih[(3+uu)*3+2];
  const float wig0 = Wih[(6+uu)*3+0], wig1 = Wih[(6+uu)*3+1], wig2 = Wih[(6+uu)*3+2];
  const float wio0 = Wih[(9+uu)*3+0], wio1 = Wih[(9+uu)*3+1], wio2 = Wih[(9+uu)*3+2];
  const float whi0 = Whh[uu*3+0],     whi1 = Whh[uu*3+1],     whi2 = Whh[uu*3+2];
  const float whf0 = Whh[(3+uu)*3+0], whf1 = Whh[(3+uu)*3+1], whf2 = Whh[(3+uu)*3+2];
  const float whg0 = Whh[(6+uu)*3+0], whg1 = Whh[(6+uu)*3+1], whg2 = Whh[(6+uu)*3+2];
  const float who0 = Whh[(9+uu)*3+0], who1 = Whh[(9+uu)*3+1], who2 = Whh[(9+uu)*3+2];
  const float bsi = bih[uu]   + bhh[uu];
  const float bsf = bih[3+uu] + bhh[3+uu];
  const float bsg = bih[6+uu] + bhh[6+uu];
  const float bso = bih[9+uu] + bhh[9+uu];

  const float dd0 = dir[3*b2c+0], dd1 = dir[3*b2c+1], dd2 = dir[3*b2c+2];

  float h0 = 0.f, h1 = 0.f, h2 = 0.f, cc = 0.f, hl = 0.f;

#define LSTEP(x0_, x1_, x2_)                                                  \
  {                                                                           \
    float zi = bsi + wii0*(x0_) + wii1*(x1_) + wii2*(x2_)                     \
                   + whi0*h0 + whi1*h1 + whi2*h2;                             \
    float zf = bsf + wif0*(x0_) + wif1*(x1_) + wif2*(x2_)                     \
                   + whf0*h0 + whf1*h1 + whf2*h2;                             \
    float zg = bsg + wig0*(x0_) + wig1*(x1_) + wig2*(x2_)                     \
                   + whg0*h0 + whg1*h1 + whg2*h2;                             \
    float zo = bso + wio0*(x0_) + wio1*(x1_) + wio2*(x2_)                     \
                   + who0*h0 + who1*h1 + who2*h2;                             \
    float ai = sigm(zi), af = sigm(zf), ag = tanh_(zg), ao = sigm(zo);        \
    cc = af*cc + ai*ag;                                                       \
    float hn = ao * tanh_(cc);                                                \
    hl = hn;                                                                  \
    h0 = quad_bcast<0x00>(hn);                                                \
    h1 = quad_bcast<0x55>(hn);                                                \
    h2 = quad_bcast<0xAA>(hn);                                                \
  }

  // 64 steps from LDS, double-buffered in 8-step chunks
  f4 xa[8], xb[8];
#pragma unroll
  for (int j = 0; j < 8; ++j) xa[j] = xrows[XIDX(j, e2)];
#pragma unroll
  for (int c = 0; c < 8; ++c) {
    if (c < 7) {
      if ((c & 1) == 0) {
#pragma unroll
        for (int j = 0; j < 8; ++j) xb[j] = xrows[XIDX((c+1)*8 + j, e2)];
      } else {
#pragma unroll
        for (int j = 0; j < 8; ++j) xa[j] = xrows[XIDX((c+1)*8 + j, e2)];
      }
    }
#pragma unroll
    for (int j = 0; j < 8; ++j) {
      f4 x = ((c & 1) == 0) ? xa[j] : xb[j];
      LSTEP(x[0], x[1], x[2]);
    }
  }
  // final step t=64 with x = dir
  LSTEP(dd0, dd1, dd2);
#undef LSTEP

  if (valid2 && u < 3) out[(size_t)b2 * 384 + 192 + u] = hl;
}

extern "C" void kernel_launch(void* const* d_in, const int* in_sizes, int n_in,
                              void* d_out, int out_size, void* d_ws, size_t ws_size,
                              hipStream_t stream) {
  const float* dir = (const float*)d_in[0];
  const float* R   = (const float*)d_in[1];
  const float* Wih = (const float*)d_in[2];
  const float* Whh = (const float*)d_in[3];
  const float* bih = (const float*)d_in[4];
  const float* bhh = (const float*)d_in[5];
  float* out = (float*)d_out;

  const int B = in_sizes[0] / 3;  // 16384
  const int grid = (B + EPB - 1) / EPB;  // 1024 blocks of 256 threads
  hipLaunchKernelGGL(fused_kernel, dim3(grid), dim3(256), 0, stream,
                     dir, R, Wih, Whh, bih, bhh, out, B);
}

// Round 7
// 35.767 us; speedup vs baseline: 2.6072x; 1.0262x over previous
//
#include <hip/hip_runtime.h>

typedef float f4 __attribute__((ext_vector_type(4)));
typedef float f4u __attribute__((ext_vector_type(4), aligned(4)));

struct M3 { float m[3][3]; };

#define ELEM(q, n) ((q)[(n) >> 2][(n) & 3])

__device__ __forceinline__ M3 matmul(const M3& A, const M3& B) {  // A @ B
  M3 C;
#pragma unroll
  for (int i = 0; i < 3; ++i)
#pragma unroll
    for (int j = 0; j < 3; ++j)
      C.m[i][j] = A.m[i][0]*B.m[0][j] + A.m[i][1]*B.m[1][j] + A.m[i][2]*B.m[2][j];
  return C;
}

// matrix k (0..3) of a 4-frame group held in 9 f4 regs; k is compile-time
__device__ __forceinline__ M3 mk(const f4 (&q)[9], int k) {
  M3 A;
#pragma unroll
  for (int i = 0; i < 3; ++i)
#pragma unroll
    for (int j = 0; j < 3; ++j)
      A.m[i][j] = ELEM(q, 9*k + 3*i + j);
  return A;
}

template <int CTRL>
__device__ __forceinline__ float dppf(float v) {
  return __int_as_float(
      __builtin_amdgcn_mov_dpp(__float_as_int(v), CTRL, 0xf, 0xf, true));
}

template <int D>  // row_shr:D within 16-lane rows (subgroups are 8-aligned)
__device__ __forceinline__ M3 dpp_shr_mat(const M3& A) {
  M3 C;
#pragma unroll
  for (int i = 0; i < 3; ++i)
#pragma unroll
    for (int j = 0; j < 3; ++j)
      C.m[i][j] = dppf<0x110 + D>(A.m[i][j]);
  return C;
}

__device__ __forceinline__ float sigm(float z) {
  return __builtin_amdgcn_rcpf(1.0f + __expf(-z));
}
__device__ __forceinline__ float tanh_(float z) {
  float e = __expf(2.0f * z);
  return 1.0f - 2.0f * __builtin_amdgcn_rcpf(e + 1.0f);
}

// quad_perm broadcast within each 4-lane quad
template <int CTRL>
__device__ __forceinline__ float quad_bcast(float v) {
  return __int_as_float(
      __builtin_amdgcn_mov_dpp(__float_as_int(v), CTRL, 0xf, 0xf, true));
}

// Blocks [0, nbBack): back chains (rows 0..63) + in-block LSTM (row 64).
// Blocks [nbBack, 2*nbBack): fwd chains (rows 65..127).
// 32 elements per block, 8 lanes per element (one 8-frame segment each).
__global__ __launch_bounds__(256, 4) void fused_kernel(
    const float* __restrict__ dir, const float* __restrict__ R,
    const float* __restrict__ Wih, const float* __restrict__ Whh,
    const float* __restrict__ bih, const float* __restrict__ bhh,
    float* __restrict__ out, int B, int nbBack) {
  __shared__ f4 xrows[64 * 33];  // [t][e] with pad-33, ~33 KB

  const int tid = threadIdx.x;
  const int e = tid >> 3;   // element 0..31 within block
  const int s = tid & 7;    // segment within chain

  if ((int)blockIdx.x < nbBack) {
    // ======================= BACK blocks =======================
    const int b = blockIdx.x * 32 + e;
    const bool valid = (b < B);
    const int bc = valid ? b : 0;
    const float* Rb = R + (size_t)bc * 1152;
    const int lo = 56 - 8 * s;  // frames lo..lo+7

    f4 qa[9], qb[9];
    {
      const f4* pA = (const f4*)(Rb + lo * 9);
      const f4* pB = (const f4*)(Rb + (lo + 4) * 9);
#pragma unroll
      for (int i = 0; i < 9; ++i) { qa[i] = pA[i]; qb[i] = pB[i]; }
    }
    const float d0 = dir[3*bc+0], d1 = dir[3*bc+1], d2 = dir[3*bc+2];

    // P = A_{lo+7} @ ... @ A_{lo}  (natural matrices, no selects)
    M3 P = mk(qa, 0);
#pragma unroll
    for (int k = 1; k < 4; ++k) P = matmul(mk(qa, k), P);
#pragma unroll
    for (int k = 0; k < 4; ++k) P = matmul(mk(qb, k), P);

    // K-scan (prev on LEFT): I_s = P_0 @ P_1 @ ... @ P_s
    M3 I = P;
    {
      M3 Sh = dpp_shr_mat<1>(I); M3 T = matmul(Sh, I);
#pragma unroll
      for (int i = 0; i < 3; ++i)
#pragma unroll
        for (int j = 0; j < 3; ++j) I.m[i][j] = (s >= 1) ? T.m[i][j] : I.m[i][j];
    }
    {
      M3 Sh = dpp_shr_mat<2>(I); M3 T = matmul(Sh, I);
#pragma unroll
      for (int i = 0; i < 3; ++i)
#pragma unroll
        for (int j = 0; j < 3; ++j) I.m[i][j] = (s >= 2) ? T.m[i][j] : I.m[i][j];
    }
    {
      M3 Sh = dpp_shr_mat<4>(I); M3 T = matmul(Sh, I);
#pragma unroll
      for (int i = 0; i < 3; ++i)
#pragma unroll
        for (int j = 0; j < 3; ++j) I.m[i][j] = (s >= 4) ? T.m[i][j] : I.m[i][j];
    }

    // w = I^T @ d = chain state after this segment's last row
    float w0 = I.m[0][0]*d0 + I.m[1][0]*d1 + I.m[2][0]*d2;
    float w1 = I.m[0][1]*d0 + I.m[1][1]*d1 + I.m[2][1]*d2;
    float w2 = I.m[0][2]*d0 + I.m[1][2]*d1 + I.m[2][2]*d2;
    float p0 = dppf<0x111>(w0), p1 = dppf<0x111>(w1), p2 = dppf<0x111>(w2);
    float v0 = (s == 0) ? d0 : p0;
    float v1 = (s == 0) ? d1 : p1;
    float v2 = (s == 0) ? d2 : p2;

    // rows r_j = A_{lo+7-j}^T @ r_{j-1}  via row-vector form v <- v^T A
    float row[24];
#pragma unroll
    for (int j = 0; j < 8; ++j) {
      M3 A = (j < 4) ? mk(qb, 3 - j) : mk(qa, 7 - j);
      float n0 = v0*A.m[0][0] + v1*A.m[1][0] + v2*A.m[2][0];
      float n1 = v0*A.m[0][1] + v1*A.m[1][1] + v2*A.m[2][1];
      float n2 = v0*A.m[0][2] + v1*A.m[1][2] + v2*A.m[2][2];
      v0 = n0; v1 = n1; v2 = n2;
      row[3*j+0] = n0; row[3*j+1] = n1; row[3*j+2] = n2;
    }

    if (valid) {  // rows 8s..8s+7 -> 24 floats, 16B-aligned: 6x dwordx4
      float* ob = out + (size_t)b * 384 + 24 * s;
#pragma unroll
      for (int kk = 0; kk < 6; ++kk) {
        f4 vv = { row[4*kk+0], row[4*kk+1], row[4*kk+2], row[4*kk+3] };
        ((f4u*)ob)[kk] = vv;
      }
    }
#pragma unroll
    for (int j = 0; j < 8; ++j) {
      f4 vv = { row[3*j+0], row[3*j+1], row[3*j+2], 0.f };
      xrows[(8*s + j) * 33 + e] = vv;
    }

    __syncthreads();

    // ---- LSTM: 4 waves x 8 elements, 4 lanes per element ----
    const int wv = tid >> 6, ln = tid & 63;
    if (ln >= 32) return;
    const int e2 = wv * 8 + (ln >> 2);
    const int u = ln & 3, uu = (u == 3) ? 0 : u;
    const int b2 = blockIdx.x * 32 + e2;
    if (b2 >= B) return;

    const float wii0 = Wih[uu*3+0],     wii1 = Wih[uu*3+1],     wii2 = Wih[uu*3+2];
    const float wif0 = Wih[(3+uu)*3+0], wif1 = Wih[(3+uu)*3+1], wif2 = Wih[(3+uu)*3+2];
    const float wig0 = Wih[(6+uu)*3+0], wig1 = Wih[(6+uu)*3+1], wig2 = Wih[(6+uu)*3+2];
    const float wio0 = Wih[(9+uu)*3+0], wio1 = Wih[(9+uu)*3+1], wio2 = Wih[(9+uu)*3+2];
    const float whi0 = Whh[uu*3+0],     whi1 = Whh[uu*3+1],     whi2 = Whh[uu*3+2];
    const float whf0 = Whh[(3+uu)*3+0], whf1 = Whh[(3+uu)*3+1], whf2 = Whh[(3+uu)*3+2];
    const float whg0 = Whh[(6+uu)*3+0], whg1 = Whh[(6+uu)*3+1], whg2 = Whh[(6+uu)*3+2];
    const float who0 = Whh[(9+uu)*3+0], who1 = Whh[(9+uu)*3+1], who2 = Whh[(9+uu)*3+2];
    const float bsi = bih[uu]   + bhh[uu];
    const float bsf = bih[3+uu] + bhh[3+uu];
    const float bsg = bih[6+uu] + bhh[6+uu];
    const float bso = bih[9+uu] + bhh[9+uu];
    const float dd0 = dir[3*b2+0], dd1 = dir[3*b2+1], dd2 = dir[3*b2+2];

    float h0 = 0.f, h1 = 0.f, h2 = 0.f, cc = 0.f, hl = 0.f;

#define LSTEP(x0_, x1_, x2_)                                                  \
  {                                                                           \
    float zi = bsi + wii0*(x0_) + wii1*(x1_) + wii2*(x2_)                     \
                   + whi0*h0 + whi1*h1 + whi2*h2;                             \
    float zf = bsf + wif0*(x0_) + wif1*(x1_) + wif2*(x2_)                     \
                   + whf0*h0 + whf1*h1 + whf2*h2;                             \
    float zg = bsg + wig0*(x0_) + wig1*(x1_) + wig2*(x2_)                     \
                   + whg0*h0 + whg1*h1 + whg2*h2;                             \
    float zo = bso + wio0*(x0_) + wio1*(x1_) + wio2*(x2_)                     \
                   + who0*h0 + who1*h1 + who2*h2;                             \
    float ai = sigm(zi), af = sigm(zf), ag = tanh_(zg), ao = sigm(zo);        \
    cc = af*cc + ai*ag;                                                       \
    float hn = ao * tanh_(cc);                                                \
    hl = hn;                                                                  \
    h0 = quad_bcast<0x00>(hn);                                                \
    h1 = quad_bcast<0x55>(hn);                                                \
    h2 = quad_bcast<0xAA>(hn);                                                \
  }

    f4 xa[8], xb[8];
#pragma unroll
    for (int j = 0; j < 8; ++j) xa[j] = xrows[j * 33 + e2];
#pragma unroll
    for (int c = 0; c < 8; ++c) {
      if (c < 7) {
        if ((c & 1) == 0) {
#pragma unroll
          for (int j = 0; j < 8; ++j) xb[j] = xrows[((c+1)*8 + j) * 33 + e2];
        } else {
#pragma unroll
          for (int j = 0; j < 8; ++j) xa[j] = xrows[((c+1)*8 + j) * 33 + e2];
        }
      }
#pragma unroll
      for (int j = 0; j < 8; ++j) {
        f4 x = ((c & 1) == 0) ? xa[j] : xb[j];
        LSTEP(x[0], x[1], x[2]);
      }
    }
    LSTEP(dd0, dd1, dd2);  // final step t=64 with x = dir
#undef LSTEP

    if (u < 3) out[(size_t)b2 * 384 + 192 + u] = hl;

  } else {
    // ======================= FWD blocks =======================
    const int b = ((int)blockIdx.x - nbBack) * 32 + e;
    const bool valid = (b < B);
    const int bc = valid ? b : 0;
    const float* Rb = R + (size_t)bc * 1152;
    const int lo = 64 + 8 * s;  // frames lo..lo+7 (s=7: frame 127 loaded, row unused)

    f4 qa[9], qb[9];
    {
      const f4* pA = (const f4*)(Rb + lo * 9);
      const f4* pB = (const f4*)(Rb + (lo + 4) * 9);
#pragma unroll
      for (int i = 0; i < 9; ++i) { qa[i] = pA[i]; qb[i] = pB[i]; }
    }
    const float d0 = dir[3*bc+0], d1 = dir[3*bc+1], d2 = dir[3*bc+2];

    M3 P = mk(qa, 0);
#pragma unroll
    for (int k = 1; k < 4; ++k) P = matmul(mk(qa, k), P);
#pragma unroll
    for (int k = 0; k < 4; ++k) P = matmul(mk(qb, k), P);

    // fwd scan: I_s = S_s @ S_{s-1} @ ... @ S_0
    M3 I = P;
    {
      M3 Sh = dpp_shr_mat<1>(I); M3 T = matmul(I, Sh);
#pragma unroll
      for (int i = 0; i < 3; ++i)
#pragma unroll
        for (int j = 0; j < 3; ++j) I.m[i][j] = (s >= 1) ? T.m[i][j] : I.m[i][j];
    }
    {
      M3 Sh = dpp_shr_mat<2>(I); M3 T = matmul(I, Sh);
#pragma unroll
      for (int i = 0; i < 3; ++i)
#pragma unroll
        for (int j = 0; j < 3; ++j) I.m[i][j] = (s >= 2) ? T.m[i][j] : I.m[i][j];
    }
    {
      M3 Sh = dpp_shr_mat<4>(I); M3 T = matmul(I, Sh);
#pragma unroll
      for (int i = 0; i < 3; ++i)
#pragma unroll
        for (int j = 0; j < 3; ++j) I.m[i][j] = (s >= 4) ? T.m[i][j] : I.m[i][j];
    }

    float w0 = I.m[0][0]*d0 + I.m[0][1]*d1 + I.m[0][2]*d2;
    float w1 = I.m[1][0]*d0 + I.m[1][1]*d1 + I.m[1][2]*d2;
    float w2 = I.m[2][0]*d0 + I.m[2][1]*d1 + I.m[2][2]*d2;
    float p0 = dppf<0x111>(w0), p1 = dppf<0x111>(w1), p2 = dppf<0x111>(w2);
    float v0 = (s == 0) ? d0 : p0;
    float v1 = (s == 0) ? d1 : p1;
    float v2 = (s == 0) ? d2 : p2;

    float row[24];
#pragma unroll
    for (int j = 0; j < 8; ++j) {
      M3 A = (j < 4) ? mk(qa, j) : mk(qb, j - 4);
      float n0 = A.m[0][0]*v0 + A.m[0][1]*v1 + A.m[0][2]*v2;
      float n1 = A.m[1][0]*v0 + A.m[1][1]*v1 + A.m[1][2]*v2;
      float n2 = A.m[2][0]*v0 + A.m[2][1]*v1 + A.m[2][2]*v2;
      v0 = n0; v1 = n1; v2 = n2;
      row[3*j+0] = n0; row[3*j+1] = n1; row[3*j+2] = n2;
    }

    if (valid) {  // rows 65+8s .. 72+8s (s=7: only 7 rows)
      float* ob = out + (size_t)b * 384 + (size_t)(65 + 8*s) * 3;
#pragma unroll
      for (int kk = 0; kk < 5; ++kk) {
        f4u vv = { row[4*kk+0], row[4*kk+1], row[4*kk+2], row[4*kk+3] };
        *(f4u*)(ob + 4*kk) = vv;
      }
      ob[20] = row[20];
      if (s < 7) { ob[21] = row[21]; ob[22] = row[22]; ob[23] = row[23]; }
    }
  }
}

extern "C" void kernel_launch(void* const* d_in, const int* in_sizes, int n_in,
                              void* d_out, int out_size, void* d_ws, size_t ws_size,
                              hipStream_t stream) {
  const float* dir = (const float*)d_in[0];
  const float* R   = (const float*)d_in[1];
  const float* Wih = (const float*)d_in[2];
  const float* Whh = (const float*)d_in[3];
  const float* bih = (const float*)d_in[4];
  const float* bhh = (const float*)d_in[5];
  float* out = (float*)d_out;

  const int B = in_sizes[0] / 3;  // 16384
  const int nbBack = (B + 31) / 32;  // 512
  const int grid = nbBack * 2;       // back blocks then fwd blocks
  hipLaunchKernelGGL(fused_kernel, dim3(grid), dim3(256), 0, stream,
                     dir, R, Wih, Whh, bih, bhh, out, B, nbBack);
}